// Round 4
// baseline (182.037 us; speedup 1.0000x reference)
//
#include <hip/hip_runtime.h>
#include <stdint.h>

// ---------------------------------------------------------------------------
// AttentionBlock: GroupNorm(32) -> qkv 1x1 -> 8-head attention (T=1024,ch=64)
//                 -> proj 1x1 + residual.  B=8, C=512, T=1024. fp32 I/O,
//                 bf16 MFMA internally.
//   xnT[b][t][c]  (t-major activations)
//   GEMM-QK: D[t][o'] = xnT x Wqk^T -> qkT[b][t][Qall|Kall]  (pre-scaled)
//   GEMM-V : D[cv][t] = Wv x xn    -> vbuf[b][cv][t]
//   attn   : flash, 128t/block, 8 waves = 4 t-quarters x 2 s-halves (split-s
//            inside the block, LDS merge) -> 16 waves/CU occupancy
//   proj   : D[o][t] = Wp x att + bias + x -> d_out
// k-map note: MFMA slot->k is a bijection that cancels between A and B, so
// QK/GEMM use the contiguous map k=8*lb+j (single ds_read_b128 per frag);
// PV uses k=(j>>2)*16+4*lb+(j&3) because P' lands in-lane in that layout.
// Scale folding: q,k weights/bias pre-scaled by sqrt(0.125*log2e) so softmax
// runs in log2 domain with NO multiplies (exp2 only).
// ---------------------------------------------------------------------------

typedef float  f32x4  __attribute__((ext_vector_type(4)));
typedef short  s16x4  __attribute__((ext_vector_type(4)));
typedef short  s16x8  __attribute__((ext_vector_type(8)));
typedef __bf16 bf16x8 __attribute__((ext_vector_type(8)));

#define QK_SCALE 0.4246609f   // sqrt(0.125 * log2(e))

__device__ __forceinline__ f32x4 mfma_bf16_16x16x32(s16x8 a, s16x8 b, f32x4 c){
  return __builtin_amdgcn_mfma_f32_16x16x32_bf16(
      __builtin_bit_cast(bf16x8, a), __builtin_bit_cast(bf16x8, b), c, 0, 0, 0);
}

__device__ __forceinline__ s16x8 cat8(s16x4 lo, s16x4 hi){
  return __builtin_shufflevector(lo, hi, 0,1,2,3,4,5,6,7);
}

__device__ __forceinline__ short f2bf(float v){
  return __builtin_bit_cast(short, static_cast<__bf16>(v));
}

// ---------------------------------------------------------------------------
// GroupNorm stats: one block per (b,g); group = 16 contiguous channels * 1024
__global__ __launch_bounds__(256) void gn_stats_kernel(const float* __restrict__ x,
                                                       float2* __restrict__ stats){
  __shared__ float ss[256], sq[256];
  const int bg = blockIdx.x;
  const float4* base = (const float4*)(x + (size_t)bg * 16384);
  float s = 0.f, q = 0.f;
  #pragma unroll
  for (int i = 0; i < 16; ++i){
    float4 v = base[threadIdx.x + i*256];
    s += v.x + v.y + v.z + v.w;
    q += v.x*v.x + v.y*v.y + v.z*v.z + v.w*v.w;
  }
  ss[threadIdx.x] = s; sq[threadIdx.x] = q;
  __syncthreads();
  for (int off = 128; off > 0; off >>= 1){
    if (threadIdx.x < off){ ss[threadIdx.x] += ss[threadIdx.x+off];
                            sq[threadIdx.x] += sq[threadIdx.x+off]; }
    __syncthreads();
  }
  if (threadIdx.x == 0){
    float mu  = ss[0] * (1.f/16384.f);
    float var = sq[0] * (1.f/16384.f) - mu*mu;   // biased (matches jnp.var)
    stats[bg] = make_float2(mu, rsqrtf(var + 1e-5f));
  }
}

// normalize + affine -> bf16 xnT[b][t][c] (transposed via LDS tile)
__global__ __launch_bounds__(256) void gn_norm_t_kernel(const float* __restrict__ x,
    const float* __restrict__ w, const float* __restrict__ bia,
    const float2* __restrict__ stats, short* __restrict__ xnT){
  const int t0 = blockIdx.x * 64, b = blockIdx.y;
  const int tid = threadIdx.x;
  __shared__ short L[64*68];                 // [c][t] pad->68
  const float* xb = x   + (size_t)b * 524288;
  short*       ob = xnT + (size_t)b * 524288;
  for (int cc = 0; cc < 8; ++cc){
    #pragma unroll
    for (int i = 0; i < 4; ++i){
      const int f  = tid + i*256;            // 0..1023
      const int cl = f >> 4, t4 = (f & 15) * 4;
      const int ch = cc*64 + cl;
      const float2 st = stats[b*32 + (ch >> 4)];
      const float sc = st.y * w[ch];
      const float sh = bia[ch] - st.x * sc;
      float4 v = *(const float4*)(xb + (size_t)ch*1024 + t0 + t4);
      s16x4 o;
      o[0]=f2bf(v.x*sc+sh); o[1]=f2bf(v.y*sc+sh); o[2]=f2bf(v.z*sc+sh); o[3]=f2bf(v.w*sc+sh);
      *(s16x4*)&L[cl*68 + t4] = o;
    }
    __syncthreads();
    #pragma unroll
    for (int i = 0; i < 2; ++i){
      const int g  = tid + i*256;            // 0..511
      const int tl = g >> 3, c8 = g & 7;
      s16x8 o;
      #pragma unroll
      for (int j = 0; j < 8; ++j) o[j] = L[(c8*8 + j)*68 + tl];
      *(s16x8*)(ob + (size_t)(t0 + tl)*512 + cc*64 + c8*8) = o;
    }
    __syncthreads();
  }
}

// fp32 -> bf16 for BOTH weight matrices in one launch.
// i < 98304: qkv_w rows (q,k rows scaled by QK_SCALE); else proj_w.
__global__ __launch_bounds__(256) void cvt_w_kernel(const float* __restrict__ qkv_w,
    const float* __restrict__ proj_w, short* __restrict__ qwb, short* __restrict__ pwb){
  const int i = blockIdx.x*256 + threadIdx.x;       // 0..131071
  const float* in; short* out; float s;
  if (i < 98304){
    in = qkv_w + (size_t)i*8; out = qwb + (size_t)i*8;
    s = (((i >> 6) % 192) < 128) ? QK_SCALE : 1.f;
  } else {
    const int j = i - 98304;
    in = proj_w + (size_t)j*8; out = pwb + (size_t)j*8;
    s = 1.f;
  }
  const float4* p = (const float4*)in;
  float4 a = p[0], b = p[1];
  s16x8 o;
  o[0]=f2bf(a.x*s); o[1]=f2bf(a.y*s); o[2]=f2bf(a.z*s); o[3]=f2bf(a.w*s);
  o[4]=f2bf(b.x*s); o[5]=f2bf(b.y*s); o[6]=f2bf(b.z*s); o[7]=f2bf(b.w*s);
  *(s16x8*)out = o;
}

// ---------------------------------------------------------------------------
// Unified K=512 GEMM, 128xNB tile (NB=128 or 64), BK=32, 4 waves (2x2).
// Frags: contiguous k-map (k=8*lb+j) -> single ds_read_b128, bank-perfect @pad40.
template<int MODE, int NB>
__global__ __launch_bounds__(256) void gemm_k512(const short* __restrict__ W,
    const short* __restrict__ act, const float* __restrict__ bias,
    const float* __restrict__ resid, void* __restrict__ outp){
  constexpr int NSF   = NB / 32;    // n-frags per wave
  constexpr int NBREG = NB / 64;    // staged uint4 per thread for B
  const int b  = blockIdx.z;
  const int m0 = blockIdx.y * 128;
  const int n0 = blockIdx.x * NB;
  const int tid  = threadIdx.x;
  const int lane = tid & 63, w = tid >> 6;
  const int wm = w >> 1, wn = w & 1;
  const int lm = lane & 15, lb = lane >> 4;

  __shared__ short As[2][128*40];
  __shared__ short Bs[2][NB*40];

  const short* actb = act + (size_t)b * 524288;

  auto arow = [&](int r) -> const short* {
    if constexpr (MODE == 0){
      return actb + (size_t)(m0 + r) * 512;
    } else if constexpr (MODE == 1){
      const int m = m0 + r;
      return W + (size_t)(192*(m>>6) + 128 + (m&63)) * 512;
    } else {
      return W + (size_t)(m0 + r) * 512;
    }
  };
  auto brow = [&](int r) -> const short* {
    if constexpr (MODE == 0){
      const int o = n0 + r;
      return W + (size_t)(192*((o>>6)&7) + (o&63) + ((o>=512)?64:0)) * 512;
    } else {
      return actb + (size_t)(n0 + r) * 512;
    }
  };

  uint4 areg[2], breg[NBREG];
  auto load_regs = [&](int t){
    const int k0 = t * 32;
    #pragma unroll
    for (int i = 0; i < 2; ++i){
      const int c = tid + i*256;
      areg[i] = *(const uint4*)(arow(c>>2) + k0 + (c&3)*8);
    }
    #pragma unroll
    for (int i = 0; i < NBREG; ++i){
      const int c = tid + i*256;
      breg[i] = *(const uint4*)(brow(c>>2) + k0 + (c&3)*8);
    }
  };
  auto write_lds = [&](int buf){
    #pragma unroll
    for (int i = 0; i < 2; ++i){
      const int c = tid + i*256;
      *(uint4*)&As[buf][(c>>2)*40 + (c&3)*8] = areg[i];
    }
    #pragma unroll
    for (int i = 0; i < NBREG; ++i){
      const int c = tid + i*256;
      *(uint4*)&Bs[buf][(c>>2)*40 + (c&3)*8] = breg[i];
    }
  };

  f32x4 acc[4][NSF] = {};
  load_regs(0);
  write_lds(0);

  for (int t = 0; t < 16; ++t){
    if (t + 1 < 16) load_regs(t + 1);
    __syncthreads();
    const int buf = t & 1;

    s16x8 af[4], bfr[NSF];
    #pragma unroll
    for (int ms = 0; ms < 4; ++ms)
      af[ms] = *(const s16x8*)&As[buf][(wm*64 + ms*16 + lm)*40 + 8*lb];
    #pragma unroll
    for (int ns = 0; ns < NSF; ++ns)
      bfr[ns] = *(const s16x8*)&Bs[buf][(wn*(NB/2) + ns*16 + lm)*40 + 8*lb];
    #pragma unroll
    for (int ns = 0; ns < NSF; ++ns)
      #pragma unroll
      for (int ms = 0; ms < 4; ++ms)
        acc[ms][ns] = mfma_bf16_16x16x32(af[ms], bfr[ns], acc[ms][ns]);

    if (t + 1 < 16) write_lds((t + 1) & 1);
  }

  // C/D: col = lane&15, row = 4*(lane>>4) + reg   (m89)
  const int mo = m0 + wm*64, no = n0 + wn*(NB/2);
  if constexpr (MODE == 0){
    short* out = (short*)outp + (size_t)b * 1048576;
    float bn[NSF];
    #pragma unroll
    for (int ns = 0; ns < NSF; ++ns){
      const int o = no + ns*16 + lm;
      bn[ns] = QK_SCALE * bias[192*((o>>6)&7) + (o&63) + ((o>=512)?64:0)];
    }
    #pragma unroll
    for (int ms = 0; ms < 4; ++ms)
      #pragma unroll
      for (int ns = 0; ns < NSF; ++ns)
        #pragma unroll
        for (int r = 0; r < 4; ++r){
          const int m = mo + ms*16 + 4*lb + r;
          const int n = no + ns*16 + lm;
          out[(size_t)m*1024 + n] = f2bf(acc[ms][ns][r] + bn[ns]);
        }
  } else if constexpr (MODE == 1){
    short* out = (short*)outp + (size_t)b * 524288;
    float bm[16];
    #pragma unroll
    for (int ms = 0; ms < 4; ++ms)
      #pragma unroll
      for (int r = 0; r < 4; ++r){
        const int m = mo + ms*16 + 4*lb + r;
        bm[ms*4+r] = bias[192*(m>>6) + 128 + (m&63)];
      }
    #pragma unroll
    for (int ms = 0; ms < 4; ++ms)
      #pragma unroll
      for (int ns = 0; ns < NSF; ++ns)
        #pragma unroll
        for (int r = 0; r < 4; ++r){
          const int m = mo + ms*16 + 4*lb + r;
          const int n = no + ns*16 + lm;
          out[(size_t)m*1024 + n] = f2bf(acc[ms][ns][r] + bm[ms*4+r]);
        }
  } else {
    float* out = (float*)outp + (size_t)b * 524288;
    const float* xr = resid + (size_t)b * 524288;
    #pragma unroll
    for (int ms = 0; ms < 4; ++ms)
      #pragma unroll
      for (int ns = 0; ns < NSF; ++ns)
        #pragma unroll
        for (int r = 0; r < 4; ++r){
          const int m = mo + ms*16 + 4*lb + r;
          const int n = no + ns*16 + lm;
          out[(size_t)m*1024 + n] = acc[ms][ns][r] + bias[m] + xr[(size_t)m*1024 + n];
        }
  }
}

// ---------------------------------------------------------------------------
// Attention v4: 512 blocks x 512 threads. bid = bh + 64*tc (XCD locality).
// Wave w: t-quarter (w&3)*32, s-half (w>>2)*512. Each half double-buffers its
// own K/V tiles; 8 iters; (m,l,O) merged through LDS at the end.
__global__ __launch_bounds__(512, 4) void attn4_kernel(const short* __restrict__ qkT,
    const short* __restrict__ vbuf, short* __restrict__ attT){
  const int bid = blockIdx.x;
  const int bh = bid & 63, tc = bid >> 6;
  const int b = bh >> 3, h = bh & 7;
  const int tid = threadIdx.x;
  const int lane = tid & 63, w = tid >> 6;
  const int wq = w & 3, half = w >> 2;
  const int lm = lane & 15, lb = lane >> 4;
  const int t0 = tc * 128;

  const short* qb = qkT + (size_t)b*1048576 + h*64;
  const short* kb = qkT + (size_t)b*1048576 + 512 + h*64 + (size_t)(half*512)*1024;
  const short* vb = vbuf + (size_t)b*524288 + (size_t)(h*64)*1024 + half*512;

  __shared__ __align__(16) char smem[71680];
  short* Kbase = (short*)smem;                 // [half][buf][64*72] = 36864 B
  short* Vbase = (short*)(smem + 36864);       // [half][buf][64*68] = 34816 B
  auto Ks = [&](int buf){ return Kbase + (half*2 + buf)*4608; };
  auto Vs = [&](int buf){ return Vbase + (half*2 + buf)*4352; };

  // Q frags straight from global (read-once), contiguous k-map
  s16x8 qf[2][2];
  #pragma unroll
  for (int tb = 0; tb < 2; ++tb)
    #pragma unroll
    for (int ks = 0; ks < 2; ++ks)
      qf[tb][ks] = *(const s16x8*)(qb + (size_t)(t0 + wq*32 + tb*16 + lm)*1024
                                      + ks*32 + 8*lb);

  uint4 kreg[2], vreg[2];
  const int g0 = tid & 255;
  auto load_kv = [&](int it){
    const int s0 = it * 64;
    #pragma unroll
    for (int i = 0; i < 2; ++i){
      const int g = g0 + i*256, r = g >> 3, c8 = g & 7;
      kreg[i] = *(const uint4*)(kb + (size_t)(s0 + r)*1024 + c8*8);
      vreg[i] = *(const uint4*)(vb + (size_t)r*1024 + s0 + c8*8);
    }
  };
  auto write_kv = [&](int buf){
    short* K = Ks(buf); short* V = Vs(buf);
    #pragma unroll
    for (int i = 0; i < 2; ++i){
      const int g = g0 + i*256, r = g >> 3, c8 = g & 7;
      *(uint4*)&K[r*72 + c8*8] = kreg[i];
      *(uint2*)&V[r*68 + c8*8]     = make_uint2(vreg[i].x, vreg[i].y);
      *(uint2*)&V[r*68 + c8*8 + 4] = make_uint2(vreg[i].z, vreg[i].w);
    }
  };

  f32x4 of[2][4] = {};
  float mrun[2] = {-1e30f, -1e30f}, lrun[2] = {0.f, 0.f};
  s16x8 pbf[2][2];

  load_kv(0);
  write_kv(0);

  for (int it = 0; it < 8; ++it){
    if (it + 1 < 8) load_kv(it + 1);
    __syncthreads();
    const int buf = it & 1;

    // QK^T: S'[s][t], contiguous k-map, single b128 K-frags
    f32x4 sf[2][4];
    #pragma unroll
    for (int tb = 0; tb < 2; ++tb)
      #pragma unroll
      for (int ms = 0; ms < 4; ++ms) sf[tb][ms] = 0.f;
    #pragma unroll
    for (int ks = 0; ks < 2; ++ks){
      s16x8 kf[4];
      #pragma unroll
      for (int ms = 0; ms < 4; ++ms)
        kf[ms] = *(const s16x8*)&Ks(buf)[(ms*16 + lm)*72 + ks*32 + 8*lb];
      #pragma unroll
      for (int ms = 0; ms < 4; ++ms){
        sf[0][ms] = mfma_bf16_16x16x32(kf[ms], qf[0][ks], sf[0][ms]);
        sf[1][ms] = mfma_bf16_16x16x32(kf[ms], qf[1][ks], sf[1][ms]);
      }
    }

    // online softmax (log2 domain), defer-max THR=8
    #pragma unroll
    for (int tb = 0; tb < 2; ++tb){
      float mt = sf[tb][0][0];
      #pragma unroll
      for (int ms = 0; ms < 4; ++ms)
        #pragma unroll
        for (int r = 0; r < 4; ++r)
          if (ms | r) mt = fmaxf(mt, sf[tb][ms][r]);
      mt = fmaxf(mt, __shfl_xor(mt, 16, 64));
      mt = fmaxf(mt, __shfl_xor(mt, 32, 64));
      const bool allskip = __all(mt <= mrun[tb] + 8.f);
      const float mnew = allskip ? mrun[tb] : fmaxf(mrun[tb], mt);
      float ps = 0.f;
      #pragma unroll
      for (int ms = 0; ms < 4; ++ms)
        #pragma unroll
        for (int r = 0; r < 4; ++r){
          const float e = exp2f(sf[tb][ms][r] - mnew);
          ps += e;
          pbf[tb][ms >> 1][(ms & 1)*4 + r] = f2bf(e);
        }
      ps += __shfl_xor(ps, 16, 64);
      ps += __shfl_xor(ps, 32, 64);
      if (allskip){
        lrun[tb] += ps;
      } else {
        const float alpha = exp2f(mrun[tb] - mnew);
        lrun[tb] = lrun[tb]*alpha + ps;
        mrun[tb] = mnew;
        #pragma unroll
        for (int cs = 0; cs < 4; ++cs) of[tb][cs] *= alpha;
      }
    }

    // PV: D[c][t] = mfma(A=V rows, B=P'); k-map (j>>2)*16+4lb+(j&3), b64 pairs
    #pragma unroll
    for (int ks2 = 0; ks2 < 2; ++ks2)
      #pragma unroll
      for (int cs = 0; cs < 4; ++cs){
        const short* pV = &Vs(buf)[(cs*16 + lm)*68 + ks2*32 + 4*lb];
        s16x8 vf = cat8(*(const s16x4*)pV, *(const s16x4*)(pV + 16));
        of[0][cs] = mfma_bf16_16x16x32(vf, pbf[0][ks2], of[0][cs]);
        of[1][cs] = mfma_bf16_16x16x32(vf, pbf[1][ks2], of[1][cs]);
      }

    if (it + 1 < 8) write_kv((it + 1) & 1);
  }

  // ---- merge the two s-halves through LDS -------------------------------
  __syncthreads();
  float* fb = (float*)smem;                    // 36 x [256] floats = 36864 B
  short* Tl = (short*)(smem + 36864);          // 128 x 72 shorts  = 18432 B
  const int base = wq*64 + lane;
  if (half == 1){
    #pragma unroll
    for (int tb = 0; tb < 2; ++tb){
      #pragma unroll
      for (int cs = 0; cs < 4; ++cs)
        #pragma unroll
        for (int r = 0; r < 4; ++r)
          fb[(tb*16 + cs*4 + r)*256 + base] = of[tb][cs][r];
      fb[(32 + tb)*256 + base] = mrun[tb];
      fb[(34 + tb)*256 + base] = lrun[tb];
    }
  }
  __syncthreads();
  if (half == 0){
    #pragma unroll
    for (int tb = 0; tb < 2; ++tb){
      const float m1 = fb[(32 + tb)*256 + base];
      const float l1 = fb[(34 + tb)*256 + base];
      const float M  = fmaxf(mrun[tb], m1);
      float a0 = exp2f(mrun[tb] - M), a1 = exp2f(m1 - M);
      const float inv = 1.f / (lrun[tb]*a0 + l1*a1);
      a0 *= inv; a1 *= inv;
      #pragma unroll
      for (int cs = 0; cs < 4; ++cs){
        s16x4 o;
        #pragma unroll
        for (int r = 0; r < 4; ++r)
          o[r] = f2bf(of[tb][cs][r]*a0 + fb[(tb*16 + cs*4 + r)*256 + base]*a1);
        *(s16x4*)&Tl[(wq*32 + tb*16 + lm)*72 + cs*16 + 4*lb] = o;
      }
    }
  }
  __syncthreads();
  short* outb = attT + (size_t)b*524288 + (size_t)t0*512 + h*64;
  #pragma unroll
  for (int i = 0; i < 2; ++i){
    const int g = tid + i*512, r = g >> 3, c8 = g & 7;
    *(uint4*)(outb + (size_t)r*512 + c8*8) = *(const uint4*)&Tl[r*72 + c8*8];
  }
}

// ---------------------------------------------------------------------------
extern "C" void kernel_launch(void* const* d_in, const int* in_sizes, int n_in,
                              void* d_out, int out_size, void* d_ws, size_t ws_size,
                              hipStream_t stream){
  const float* x      = (const float*)d_in[0];
  const float* norm_w = (const float*)d_in[1];
  const float* norm_b = (const float*)d_in[2];
  const float* qkv_w  = (const float*)d_in[3];
  const float* qkv_b  = (const float*)d_in[4];
  const float* proj_w = (const float*)d_in[5];
  const float* proj_b = (const float*)d_in[6];

  char* ws = (char*)d_ws;
  float2* stats = (float2*)(ws);                                   //   4 KB
  short*  xnT   = (short*)(ws + 4096);                             //   8 MiB
  short*  qwb   = (short*)(ws + 4096 + 8388608);                   // 1.5 MiB
  short*  pwb   = (short*)(ws + 4096 + 8388608 + 1572864);         // 0.5 MiB
  short*  qkT   = (short*)(ws + 4096 + 8388608 + 1572864 + 524288);            // 16 MiB
  short*  vbuf  = (short*)(ws + 4096 + 8388608 + 1572864 + 524288 + 16777216); //  8 MiB
  short*  attT  = (short*)(ws + 4096 + 8388608 + 1572864 + 524288 + 16777216 + 8388608); // 8 MiB

  gn_stats_kernel<<<dim3(256), dim3(256), 0, stream>>>(x, stats);
  gn_norm_t_kernel<<<dim3(16, 8), dim3(256), 0, stream>>>(x, norm_w, norm_b, stats, xnT);
  cvt_w_kernel<<<dim3(512), dim3(256), 0, stream>>>(qkv_w, proj_w, qwb, pwb);
  gemm_k512<0,128><<<dim3(8, 8, 8), dim3(256), 0, stream>>>(qwb, xnT, qkv_b, nullptr, (void*)qkT);
  gemm_k512<1,64><<<dim3(16, 4, 8), dim3(256), 0, stream>>>(qwb, xnT, qkv_b, nullptr, (void*)vbuf);
  attn4_kernel<<<dim3(512), dim3(512), 0, stream>>>(qkT, vbuf, attT);
  gemm_k512<2,64><<<dim3(16, 4, 8), dim3(256), 0, stream>>>(pwb, attT, proj_b, x, d_out);
}

// Round 5
// 170.189 us; speedup vs baseline: 1.0696x; 1.0696x over previous
//
#include <hip/hip_runtime.h>
#include <stdint.h>

// ---------------------------------------------------------------------------
// AttentionBlock: GroupNorm(32) -> qkv 1x1 -> 8-head attention (T=1024,ch=64)
//                 -> proj 1x1 + residual.  B=8, C=512, T=1024. fp32 I/O,
//                 bf16 MFMA internally.
//   xnT[b][t][c]  (t-major activations)
//   GEMM-QK: D[t][o'] = xnT x Wqk^T -> qkT[b][t][Qall|Kall]  (pre-scaled)
//   GEMM-V : D[cv][t] = Wv x xn    -> vbuf[b][cv][t]
//   attn   : flash, 128t/block, 8 waves = 4 t-quarters x 2 s-halves (split-s
//            inside the block, LDS merge) -> 16 waves/CU occupancy
//   proj   : D[o][t] = Wp x att + bias + x -> d_out
// k-map note: MFMA slot->k is a bijection that cancels between A and B, so
// QK/GEMM use the contiguous map k=8*lb+j (single ds_read_b128 per frag);
// PV uses k=(j>>2)*16+4*lb+(j&3) because P' lands in-lane in that layout.
// Scale folding: q,k weights/bias pre-scaled by sqrt(0.125*log2e) so softmax
// runs in log2 domain with NO multiplies (exp2 only).
// R4 lesson: __launch_bounds__(512,4) capped VGPR at 64 -> ~110 live regs
// spilled to scratch (WRITE_SIZE 12.5->145 MB). Use (512,2): LDS caps
// occupancy at 2 blocks/CU anyway; no spills.
// ---------------------------------------------------------------------------

typedef float  f32x4  __attribute__((ext_vector_type(4)));
typedef short  s16x4  __attribute__((ext_vector_type(4)));
typedef short  s16x8  __attribute__((ext_vector_type(8)));
typedef __bf16 bf16x8 __attribute__((ext_vector_type(8)));

#define QK_SCALE 0.4246609f   // sqrt(0.125 * log2(e))

__device__ __forceinline__ f32x4 mfma_bf16_16x16x32(s16x8 a, s16x8 b, f32x4 c){
  return __builtin_amdgcn_mfma_f32_16x16x32_bf16(
      __builtin_bit_cast(bf16x8, a), __builtin_bit_cast(bf16x8, b), c, 0, 0, 0);
}

__device__ __forceinline__ s16x8 cat8(s16x4 lo, s16x4 hi){
  return __builtin_shufflevector(lo, hi, 0,1,2,3,4,5,6,7);
}

__device__ __forceinline__ short f2bf(float v){
  return __builtin_bit_cast(short, static_cast<__bf16>(v));
}

// ---------------------------------------------------------------------------
// GroupNorm stats: one block per (b,g); group = 16 contiguous channels * 1024
__global__ __launch_bounds__(256) void gn_stats_kernel(const float* __restrict__ x,
                                                       float2* __restrict__ stats){
  __shared__ float ss[256], sq[256];
  const int bg = blockIdx.x;
  const float4* base = (const float4*)(x + (size_t)bg * 16384);
  float s = 0.f, q = 0.f;
  #pragma unroll
  for (int i = 0; i < 16; ++i){
    float4 v = base[threadIdx.x + i*256];
    s += v.x + v.y + v.z + v.w;
    q += v.x*v.x + v.y*v.y + v.z*v.z + v.w*v.w;
  }
  ss[threadIdx.x] = s; sq[threadIdx.x] = q;
  __syncthreads();
  for (int off = 128; off > 0; off >>= 1){
    if (threadIdx.x < off){ ss[threadIdx.x] += ss[threadIdx.x+off];
                            sq[threadIdx.x] += sq[threadIdx.x+off]; }
    __syncthreads();
  }
  if (threadIdx.x == 0){
    float mu  = ss[0] * (1.f/16384.f);
    float var = sq[0] * (1.f/16384.f) - mu*mu;   // biased (matches jnp.var)
    stats[bg] = make_float2(mu, rsqrtf(var + 1e-5f));
  }
}

// normalize + affine -> bf16 xnT[b][t][c] (transposed via LDS tile)
__global__ __launch_bounds__(256) void gn_norm_t_kernel(const float* __restrict__ x,
    const float* __restrict__ w, const float* __restrict__ bia,
    const float2* __restrict__ stats, short* __restrict__ xnT){
  const int t0 = blockIdx.x * 64, b = blockIdx.y;
  const int tid = threadIdx.x;
  __shared__ short L[64*68];                 // [c][t] pad->68
  const float* xb = x   + (size_t)b * 524288;
  short*       ob = xnT + (size_t)b * 524288;
  for (int cc = 0; cc < 8; ++cc){
    #pragma unroll
    for (int i = 0; i < 4; ++i){
      const int f  = tid + i*256;            // 0..1023
      const int cl = f >> 4, t4 = (f & 15) * 4;
      const int ch = cc*64 + cl;
      const float2 st = stats[b*32 + (ch >> 4)];
      const float sc = st.y * w[ch];
      const float sh = bia[ch] - st.x * sc;
      float4 v = *(const float4*)(xb + (size_t)ch*1024 + t0 + t4);
      s16x4 o;
      o[0]=f2bf(v.x*sc+sh); o[1]=f2bf(v.y*sc+sh); o[2]=f2bf(v.z*sc+sh); o[3]=f2bf(v.w*sc+sh);
      *(s16x4*)&L[cl*68 + t4] = o;
    }
    __syncthreads();
    #pragma unroll
    for (int i = 0; i < 2; ++i){
      const int g  = tid + i*256;            // 0..511
      const int tl = g >> 3, c8 = g & 7;
      s16x8 o;
      #pragma unroll
      for (int j = 0; j < 8; ++j) o[j] = L[(c8*8 + j)*68 + tl];
      *(s16x8*)(ob + (size_t)(t0 + tl)*512 + cc*64 + c8*8) = o;
    }
    __syncthreads();
  }
}

// fp32 -> bf16 for BOTH weight matrices in one launch.
// i < 98304: qkv_w rows (q,k rows scaled by QK_SCALE); else proj_w.
__global__ __launch_bounds__(256) void cvt_w_kernel(const float* __restrict__ qkv_w,
    const float* __restrict__ proj_w, short* __restrict__ qwb, short* __restrict__ pwb){
  const int i = blockIdx.x*256 + threadIdx.x;       // 0..131071
  const float* in; short* out; float s;
  if (i < 98304){
    in = qkv_w + (size_t)i*8; out = qwb + (size_t)i*8;
    s = (((i >> 6) % 192) < 128) ? QK_SCALE : 1.f;
  } else {
    const int j = i - 98304;
    in = proj_w + (size_t)j*8; out = pwb + (size_t)j*8;
    s = 1.f;
  }
  const float4* p = (const float4*)in;
  float4 a = p[0], b = p[1];
  s16x8 o;
  o[0]=f2bf(a.x*s); o[1]=f2bf(a.y*s); o[2]=f2bf(a.z*s); o[3]=f2bf(a.w*s);
  o[4]=f2bf(b.x*s); o[5]=f2bf(b.y*s); o[6]=f2bf(b.z*s); o[7]=f2bf(b.w*s);
  *(s16x8*)out = o;
}

// ---------------------------------------------------------------------------
// Unified K=512 GEMM, 128xNB tile (NB=128 or 64), BK=32, 4 waves (2x2).
// Frags: contiguous k-map (k=8*lb+j) -> single ds_read_b128, bank-perfect @pad40.
template<int MODE, int NB>
__global__ __launch_bounds__(256) void gemm_k512(const short* __restrict__ W,
    const short* __restrict__ act, const float* __restrict__ bias,
    const float* __restrict__ resid, void* __restrict__ outp){
  constexpr int NSF   = NB / 32;    // n-frags per wave
  constexpr int NBREG = NB / 64;    // staged uint4 per thread for B
  const int b  = blockIdx.z;
  const int m0 = blockIdx.y * 128;
  const int n0 = blockIdx.x * NB;
  const int tid  = threadIdx.x;
  const int lane = tid & 63, w = tid >> 6;
  const int wm = w >> 1, wn = w & 1;
  const int lm = lane & 15, lb = lane >> 4;

  __shared__ short As[2][128*40];
  __shared__ short Bs[2][NB*40];

  const short* actb = act + (size_t)b * 524288;

  auto arow = [&](int r) -> const short* {
    if constexpr (MODE == 0){
      return actb + (size_t)(m0 + r) * 512;
    } else if constexpr (MODE == 1){
      const int m = m0 + r;
      return W + (size_t)(192*(m>>6) + 128 + (m&63)) * 512;
    } else {
      return W + (size_t)(m0 + r) * 512;
    }
  };
  auto brow = [&](int r) -> const short* {
    if constexpr (MODE == 0){
      const int o = n0 + r;
      return W + (size_t)(192*((o>>6)&7) + (o&63) + ((o>=512)?64:0)) * 512;
    } else {
      return actb + (size_t)(n0 + r) * 512;
    }
  };

  uint4 areg[2], breg[NBREG];
  auto load_regs = [&](int t){
    const int k0 = t * 32;
    #pragma unroll
    for (int i = 0; i < 2; ++i){
      const int c = tid + i*256;
      areg[i] = *(const uint4*)(arow(c>>2) + k0 + (c&3)*8);
    }
    #pragma unroll
    for (int i = 0; i < NBREG; ++i){
      const int c = tid + i*256;
      breg[i] = *(const uint4*)(brow(c>>2) + k0 + (c&3)*8);
    }
  };
  auto write_lds = [&](int buf){
    #pragma unroll
    for (int i = 0; i < 2; ++i){
      const int c = tid + i*256;
      *(uint4*)&As[buf][(c>>2)*40 + (c&3)*8] = areg[i];
    }
    #pragma unroll
    for (int i = 0; i < NBREG; ++i){
      const int c = tid + i*256;
      *(uint4*)&Bs[buf][(c>>2)*40 + (c&3)*8] = breg[i];
    }
  };

  f32x4 acc[4][NSF] = {};
  load_regs(0);
  write_lds(0);

  for (int t = 0; t < 16; ++t){
    if (t + 1 < 16) load_regs(t + 1);
    __syncthreads();
    const int buf = t & 1;

    s16x8 af[4], bfr[NSF];
    #pragma unroll
    for (int ms = 0; ms < 4; ++ms)
      af[ms] = *(const s16x8*)&As[buf][(wm*64 + ms*16 + lm)*40 + 8*lb];
    #pragma unroll
    for (int ns = 0; ns < NSF; ++ns)
      bfr[ns] = *(const s16x8*)&Bs[buf][(wn*(NB/2) + ns*16 + lm)*40 + 8*lb];
    #pragma unroll
    for (int ns = 0; ns < NSF; ++ns)
      #pragma unroll
      for (int ms = 0; ms < 4; ++ms)
        acc[ms][ns] = mfma_bf16_16x16x32(af[ms], bfr[ns], acc[ms][ns]);

    if (t + 1 < 16) write_lds((t + 1) & 1);
  }

  // C/D: col = lane&15, row = 4*(lane>>4) + reg   (m89)
  const int mo = m0 + wm*64, no = n0 + wn*(NB/2);
  if constexpr (MODE == 0){
    short* out = (short*)outp + (size_t)b * 1048576;
    float bn[NSF];
    #pragma unroll
    for (int ns = 0; ns < NSF; ++ns){
      const int o = no + ns*16 + lm;
      bn[ns] = QK_SCALE * bias[192*((o>>6)&7) + (o&63) + ((o>=512)?64:0)];
    }
    #pragma unroll
    for (int ms = 0; ms < 4; ++ms)
      #pragma unroll
      for (int ns = 0; ns < NSF; ++ns)
        #pragma unroll
        for (int r = 0; r < 4; ++r){
          const int m = mo + ms*16 + 4*lb + r;
          const int n = no + ns*16 + lm;
          out[(size_t)m*1024 + n] = f2bf(acc[ms][ns][r] + bn[ns]);
        }
  } else if constexpr (MODE == 1){
    short* out = (short*)outp + (size_t)b * 524288;
    float bm[16];
    #pragma unroll
    for (int ms = 0; ms < 4; ++ms)
      #pragma unroll
      for (int r = 0; r < 4; ++r){
        const int m = mo + ms*16 + 4*lb + r;
        bm[ms*4+r] = bias[192*(m>>6) + 128 + (m&63)];
      }
    #pragma unroll
    for (int ms = 0; ms < 4; ++ms)
      #pragma unroll
      for (int ns = 0; ns < NSF; ++ns)
        #pragma unroll
        for (int r = 0; r < 4; ++r){
          const int m = mo + ms*16 + 4*lb + r;
          const int n = no + ns*16 + lm;
          out[(size_t)m*1024 + n] = f2bf(acc[ms][ns][r] + bm[ms*4+r]);
        }
  } else {
    float* out = (float*)outp + (size_t)b * 524288;
    const float* xr = resid + (size_t)b * 524288;
    #pragma unroll
    for (int ms = 0; ms < 4; ++ms)
      #pragma unroll
      for (int ns = 0; ns < NSF; ++ns)
        #pragma unroll
        for (int r = 0; r < 4; ++r){
          const int m = mo + ms*16 + 4*lb + r;
          const int n = no + ns*16 + lm;
          out[(size_t)m*1024 + n] = acc[ms][ns][r] + bias[m] + xr[(size_t)m*1024 + n];
        }
  }
}

// ---------------------------------------------------------------------------
// Attention v5: 512 blocks x 512 threads. bid = bh + 64*tc (XCD locality).
// Wave w: t-quarter (w&3)*32, s-half (w>>2)*512. Each half double-buffers its
// own K/V tiles; 8 iters; (m,l,O) merged through LDS at the end.
// launch_bounds (512,2): no VGPR cap below need (~110); LDS caps at 2 blk/CU.
__global__ __launch_bounds__(512, 2) void attn5_kernel(const short* __restrict__ qkT,
    const short* __restrict__ vbuf, short* __restrict__ attT){
  const int bid = blockIdx.x;
  const int bh = bid & 63, tc = bid >> 6;
  const int b = bh >> 3, h = bh & 7;
  const int tid = threadIdx.x;
  const int lane = tid & 63, w = tid >> 6;
  const int wq = w & 3, half = w >> 2;
  const int lm = lane & 15, lb = lane >> 4;
  const int t0 = tc * 128;

  const short* qb = qkT + (size_t)b*1048576 + h*64;
  const short* kb = qkT + (size_t)b*1048576 + 512 + h*64 + (size_t)(half*512)*1024;
  const short* vb = vbuf + (size_t)b*524288 + (size_t)(h*64)*1024 + half*512;

  __shared__ __align__(16) char smem[71680];
  short* Kbase = (short*)smem;                 // [half][buf][64*72] = 36864 B
  short* Vbase = (short*)(smem + 36864);       // [half][buf][64*68] = 34816 B
  auto Ks = [&](int buf){ return Kbase + (half*2 + buf)*4608; };
  auto Vs = [&](int buf){ return Vbase + (half*2 + buf)*4352; };

  // Q frags straight from global (read-once), contiguous k-map
  s16x8 qf[2][2];
  #pragma unroll
  for (int tb = 0; tb < 2; ++tb)
    #pragma unroll
    for (int ks = 0; ks < 2; ++ks)
      qf[tb][ks] = *(const s16x8*)(qb + (size_t)(t0 + wq*32 + tb*16 + lm)*1024
                                      + ks*32 + 8*lb);

  uint4 kreg[2], vreg[2];
  const int g0 = tid & 255;
  auto load_kv = [&](int it){
    const int s0 = it * 64;
    #pragma unroll
    for (int i = 0; i < 2; ++i){
      const int g = g0 + i*256, r = g >> 3, c8 = g & 7;
      kreg[i] = *(const uint4*)(kb + (size_t)(s0 + r)*1024 + c8*8);
      vreg[i] = *(const uint4*)(vb + (size_t)r*1024 + s0 + c8*8);
    }
  };
  auto write_kv = [&](int buf){
    short* K = Ks(buf); short* V = Vs(buf);
    #pragma unroll
    for (int i = 0; i < 2; ++i){
      const int g = g0 + i*256, r = g >> 3, c8 = g & 7;
      *(uint4*)&K[r*72 + c8*8] = kreg[i];
      *(uint2*)&V[r*68 + c8*8]     = make_uint2(vreg[i].x, vreg[i].y);
      *(uint2*)&V[r*68 + c8*8 + 4] = make_uint2(vreg[i].z, vreg[i].w);
    }
  };

  f32x4 of[2][4] = {};
  float mrun[2] = {-1e30f, -1e30f}, lrun[2] = {0.f, 0.f};
  s16x8 pbf[2][2];

  load_kv(0);
  write_kv(0);

  for (int it = 0; it < 8; ++it){
    if (it + 1 < 8) load_kv(it + 1);
    __syncthreads();
    const int buf = it & 1;

    // QK^T: S'[s][t], contiguous k-map, single b128 K-frags
    f32x4 sf[2][4];
    #pragma unroll
    for (int tb = 0; tb < 2; ++tb)
      #pragma unroll
      for (int ms = 0; ms < 4; ++ms) sf[tb][ms] = 0.f;
    __builtin_amdgcn_s_setprio(1);
    #pragma unroll
    for (int ks = 0; ks < 2; ++ks){
      s16x8 kf[4];
      #pragma unroll
      for (int ms = 0; ms < 4; ++ms)
        kf[ms] = *(const s16x8*)&Ks(buf)[(ms*16 + lm)*72 + ks*32 + 8*lb];
      #pragma unroll
      for (int ms = 0; ms < 4; ++ms){
        sf[0][ms] = mfma_bf16_16x16x32(kf[ms], qf[0][ks], sf[0][ms]);
        sf[1][ms] = mfma_bf16_16x16x32(kf[ms], qf[1][ks], sf[1][ms]);
      }
    }
    __builtin_amdgcn_s_setprio(0);

    // online softmax (log2 domain), defer-max THR=8
    #pragma unroll
    for (int tb = 0; tb < 2; ++tb){
      float mt = sf[tb][0][0];
      #pragma unroll
      for (int ms = 0; ms < 4; ++ms)
        #pragma unroll
        for (int r = 0; r < 4; ++r)
          if (ms | r) mt = fmaxf(mt, sf[tb][ms][r]);
      mt = fmaxf(mt, __shfl_xor(mt, 16, 64));
      mt = fmaxf(mt, __shfl_xor(mt, 32, 64));
      const bool allskip = __all(mt <= mrun[tb] + 8.f);
      const float mnew = allskip ? mrun[tb] : fmaxf(mrun[tb], mt);
      float ps = 0.f;
      #pragma unroll
      for (int ms = 0; ms < 4; ++ms)
        #pragma unroll
        for (int r = 0; r < 4; ++r){
          const float e = exp2f(sf[tb][ms][r] - mnew);
          ps += e;
          pbf[tb][ms >> 1][(ms & 1)*4 + r] = f2bf(e);
        }
      ps += __shfl_xor(ps, 16, 64);
      ps += __shfl_xor(ps, 32, 64);
      if (allskip){
        lrun[tb] += ps;
      } else {
        const float alpha = exp2f(mrun[tb] - mnew);
        lrun[tb] = lrun[tb]*alpha + ps;
        mrun[tb] = mnew;
        #pragma unroll
        for (int cs = 0; cs < 4; ++cs) of[tb][cs] *= alpha;
      }
    }

    // PV: D[c][t] = mfma(A=V rows, B=P'); k-map (j>>2)*16+4lb+(j&3), b64 pairs
    __builtin_amdgcn_s_setprio(1);
    #pragma unroll
    for (int ks2 = 0; ks2 < 2; ++ks2)
      #pragma unroll
      for (int cs = 0; cs < 4; ++cs){
        const short* pV = &Vs(buf)[(cs*16 + lm)*68 + ks2*32 + 4*lb];
        s16x8 vf = cat8(*(const s16x4*)pV, *(const s16x4*)(pV + 16));
        of[0][cs] = mfma_bf16_16x16x32(vf, pbf[0][ks2], of[0][cs]);
        of[1][cs] = mfma_bf16_16x16x32(vf, pbf[1][ks2], of[1][cs]);
      }
    __builtin_amdgcn_s_setprio(0);

    if (it + 1 < 8) write_kv((it + 1) & 1);
  }

  // ---- merge the two s-halves through LDS -------------------------------
  __syncthreads();
  float* fb = (float*)smem;                    // 36 x [256] floats = 36864 B
  short* Tl = (short*)(smem + 36864);          // 128 x 72 shorts  = 18432 B
  const int base = wq*64 + lane;
  if (half == 1){
    #pragma unroll
    for (int tb = 0; tb < 2; ++tb){
      #pragma unroll
      for (int cs = 0; cs < 4; ++cs)
        #pragma unroll
        for (int r = 0; r < 4; ++r)
          fb[(tb*16 + cs*4 + r)*256 + base] = of[tb][cs][r];
      fb[(32 + tb)*256 + base] = mrun[tb];
      fb[(34 + tb)*256 + base] = lrun[tb];
    }
  }
  __syncthreads();
  if (half == 0){
    #pragma unroll
    for (int tb = 0; tb < 2; ++tb){
      const float m1 = fb[(32 + tb)*256 + base];
      const float l1 = fb[(34 + tb)*256 + base];
      const float M  = fmaxf(mrun[tb], m1);
      float a0 = exp2f(mrun[tb] - M), a1 = exp2f(m1 - M);
      const float inv = 1.f / (lrun[tb]*a0 + l1*a1);
      a0 *= inv; a1 *= inv;
      #pragma unroll
      for (int cs = 0; cs < 4; ++cs){
        s16x4 o;
        #pragma unroll
        for (int r = 0; r < 4; ++r)
          o[r] = f2bf(of[tb][cs][r]*a0 + fb[(tb*16 + cs*4 + r)*256 + base]*a1);
        *(s16x4*)&Tl[(wq*32 + tb*16 + lm)*72 + cs*16 + 4*lb] = o;
      }
    }
  }
  __syncthreads();
  short* outb = attT + (size_t)b*524288 + (size_t)t0*512 + h*64;
  #pragma unroll
  for (int i = 0; i < 2; ++i){
    const int g = tid + i*512, r = g >> 3, c8 = g & 7;
    *(uint4*)(outb + (size_t)r*512 + c8*8) = *(const uint4*)&Tl[r*72 + c8*8];
  }
}

// ---------------------------------------------------------------------------
extern "C" void kernel_launch(void* const* d_in, const int* in_sizes, int n_in,
                              void* d_out, int out_size, void* d_ws, size_t ws_size,
                              hipStream_t stream){
  const float* x      = (const float*)d_in[0];
  const float* norm_w = (const float*)d_in[1];
  const float* norm_b = (const float*)d_in[2];
  const float* qkv_w  = (const float*)d_in[3];
  const float* qkv_b  = (const float*)d_in[4];
  const float* proj_w = (const float*)d_in[5];
  const float* proj_b = (const float*)d_in[6];

  char* ws = (char*)d_ws;
  float2* stats = (float2*)(ws);                                   //   4 KB
  short*  xnT   = (short*)(ws + 4096);                             //   8 MiB
  short*  qwb   = (short*)(ws + 4096 + 8388608);                   // 1.5 MiB
  short*  pwb   = (short*)(ws + 4096 + 8388608 + 1572864);         // 0.5 MiB
  short*  qkT   = (short*)(ws + 4096 + 8388608 + 1572864 + 524288);            // 16 MiB
  short*  vbuf  = (short*)(ws + 4096 + 8388608 + 1572864 + 524288 + 16777216); //  8 MiB
  short*  attT  = (short*)(ws + 4096 + 8388608 + 1572864 + 524288 + 16777216 + 8388608); // 8 MiB

  gn_stats_kernel<<<dim3(256), dim3(256), 0, stream>>>(x, stats);
  gn_norm_t_kernel<<<dim3(16, 8), dim3(256), 0, stream>>>(x, norm_w, norm_b, stats, xnT);
  cvt_w_kernel<<<dim3(512), dim3(256), 0, stream>>>(qkv_w, proj_w, qwb, pwb);
  gemm_k512<0,128><<<dim3(8, 8, 8), dim3(256), 0, stream>>>(qwb, xnT, qkv_b, nullptr, (void*)qkT);
  gemm_k512<1,64><<<dim3(16, 4, 8), dim3(256), 0, stream>>>(qwb, xnT, qkv_b, nullptr, (void*)vbuf);
  attn5_kernel<<<dim3(512), dim3(512), 0, stream>>>(qkT, vbuf, attT);
  gemm_k512<2,64><<<dim3(16, 4, 8), dim3(256), 0, stream>>>(pwb, attT, proj_b, x, d_out);
}

// Round 6
// 113.945 us; speedup vs baseline: 1.5976x; 1.4936x over previous
//
#include <hip/hip_runtime.h>
#include <stdint.h>

// ---------------------------------------------------------------------------
// AttentionBlock: GroupNorm(32) -> qkv 1x1 -> 8-head attention (T=1024,ch=64)
//                 -> proj 1x1 + residual.  B=8, C=512, T=1024. fp32 I/O,
//                 bf16 MFMA internally.
//   xnT[b][t][c]  (t-major activations)
//   GEMM-QK: D[t][o'] = xnT x Wqk^T -> qkT[b][t][Qall|Kall]  (pre-scaled)
//   GEMM-V : D[cv][t] = Wv x xn    -> vbuf[b][cv][t]
//   attn   : flash, 128t/block, 4 waves x 32t, KVBLK=64, dbuf (attn3 struct)
//   proj   : D[o][t] = Wp x att + bias + x -> d_out
// GEMM staging: global_load_lds width=16, linear [row][32] LDS + XOR swizzle
//   slot = lb ^ ((row>>1)&3), source chunk pre-swizzled (both-sides rule).
// attn: l-sum deferred to epilogue (per-lane partials); max-reduce only 2
//   shuffles/tb; log2-domain softmax (scales folded into q,k weights).
// R4/R5 lessons: never launch_bounds-cap below live regs (spills);
//   usable LDS/CU ~128KB -> keep block LDS <= 36KB for 2 blk/CU residency.
// ---------------------------------------------------------------------------

typedef float  f32x4  __attribute__((ext_vector_type(4)));
typedef short  s16x4  __attribute__((ext_vector_type(4)));
typedef short  s16x8  __attribute__((ext_vector_type(8)));
typedef __bf16 bf16x8 __attribute__((ext_vector_type(8)));

#define QK_SCALE 0.4246609f   // sqrt(0.125 * log2(e))
#define FMAX3(a,b,c) fmaxf(fmaxf(a,b),c)

__device__ __forceinline__ f32x4 mfma_bf16_16x16x32(s16x8 a, s16x8 b, f32x4 c){
  return __builtin_amdgcn_mfma_f32_16x16x32_bf16(
      __builtin_bit_cast(bf16x8, a), __builtin_bit_cast(bf16x8, b), c, 0, 0, 0);
}

__device__ __forceinline__ s16x8 cat8(s16x4 lo, s16x4 hi){
  return __builtin_shufflevector(lo, hi, 0,1,2,3,4,5,6,7);
}

__device__ __forceinline__ short f2bf(float v){
  return __builtin_bit_cast(short, static_cast<__bf16>(v));
}

// async global->LDS, 16B per lane; dest = firstlane-base + lane*16 (linear)
__device__ __forceinline__ void gload16(const void* g, void* l){
  __builtin_amdgcn_global_load_lds(
      (const __attribute__((address_space(1))) void*)g,
      (__attribute__((address_space(3))) void*)l, 16, 0, 0);
}

// ---------------------------------------------------------------------------
// GroupNorm stats: one block per (b,g); group = 16 contiguous channels * 1024
__global__ __launch_bounds__(256) void gn_stats_kernel(const float* __restrict__ x,
                                                       float2* __restrict__ stats){
  __shared__ float ss[256], sq[256];
  const int bg = blockIdx.x;
  const float4* base = (const float4*)(x + (size_t)bg * 16384);
  float s = 0.f, q = 0.f;
  #pragma unroll
  for (int i = 0; i < 16; ++i){
    float4 v = base[threadIdx.x + i*256];
    s += v.x + v.y + v.z + v.w;
    q += v.x*v.x + v.y*v.y + v.z*v.z + v.w*v.w;
  }
  ss[threadIdx.x] = s; sq[threadIdx.x] = q;
  __syncthreads();
  for (int off = 128; off > 0; off >>= 1){
    if (threadIdx.x < off){ ss[threadIdx.x] += ss[threadIdx.x+off];
                            sq[threadIdx.x] += sq[threadIdx.x+off]; }
    __syncthreads();
  }
  if (threadIdx.x == 0){
    float mu  = ss[0] * (1.f/16384.f);
    float var = sq[0] * (1.f/16384.f) - mu*mu;   // biased (matches jnp.var)
    stats[bg] = make_float2(mu, rsqrtf(var + 1e-5f));
  }
}

// normalize + affine -> bf16 xnT[b][t][c] (transposed via LDS tile)
__global__ __launch_bounds__(256) void gn_norm_t_kernel(const float* __restrict__ x,
    const float* __restrict__ w, const float* __restrict__ bia,
    const float2* __restrict__ stats, short* __restrict__ xnT){
  const int t0 = blockIdx.x * 64, b = blockIdx.y;
  const int tid = threadIdx.x;
  __shared__ short L[64*68];                 // [c][t] pad->68
  const float* xb = x   + (size_t)b * 524288;
  short*       ob = xnT + (size_t)b * 524288;
  for (int cc = 0; cc < 8; ++cc){
    #pragma unroll
    for (int i = 0; i < 4; ++i){
      const int f  = tid + i*256;            // 0..1023
      const int cl = f >> 4, t4 = (f & 15) * 4;
      const int ch = cc*64 + cl;
      const float2 st = stats[b*32 + (ch >> 4)];
      const float sc = st.y * w[ch];
      const float sh = bia[ch] - st.x * sc;
      float4 v = *(const float4*)(xb + (size_t)ch*1024 + t0 + t4);
      s16x4 o;
      o[0]=f2bf(v.x*sc+sh); o[1]=f2bf(v.y*sc+sh); o[2]=f2bf(v.z*sc+sh); o[3]=f2bf(v.w*sc+sh);
      *(s16x4*)&L[cl*68 + t4] = o;
    }
    __syncthreads();
    #pragma unroll
    for (int i = 0; i < 2; ++i){
      const int g  = tid + i*256;            // 0..511
      const int tl = g >> 3, c8 = g & 7;
      s16x8 o;
      #pragma unroll
      for (int j = 0; j < 8; ++j) o[j] = L[(c8*8 + j)*68 + tl];
      *(s16x8*)(ob + (size_t)(t0 + tl)*512 + cc*64 + c8*8) = o;
    }
    __syncthreads();
  }
}

// fp32 -> bf16 for BOTH weight matrices in one launch.
__global__ __launch_bounds__(256) void cvt_w_kernel(const float* __restrict__ qkv_w,
    const float* __restrict__ proj_w, short* __restrict__ qwb, short* __restrict__ pwb){
  const int i = blockIdx.x*256 + threadIdx.x;       // 0..131071
  const float* in; short* out; float s;
  if (i < 98304){
    in = qkv_w + (size_t)i*8; out = qwb + (size_t)i*8;
    s = (((i >> 6) % 192) < 128) ? QK_SCALE : 1.f;
  } else {
    const int j = i - 98304;
    in = proj_w + (size_t)j*8; out = pwb + (size_t)j*8;
    s = 1.f;
  }
  const float4* p = (const float4*)in;
  float4 a = p[0], b = p[1];
  s16x8 o;
  o[0]=f2bf(a.x*s); o[1]=f2bf(a.y*s); o[2]=f2bf(a.z*s); o[3]=f2bf(a.w*s);
  o[4]=f2bf(b.x*s); o[5]=f2bf(b.y*s); o[6]=f2bf(b.z*s); o[7]=f2bf(b.w*s);
  *(s16x8*)out = o;
}

// ---------------------------------------------------------------------------
// Unified K=512 GEMM, 128xNB tile (NB=128 or 64), BK=32, 4 waves (2x2).
// Staging: global_load_lds w=16 into linear [row][32] tiles; XOR swizzle
// slot = lb ^ ((row>>1)&3) on reads, source chunk (c&3)^((c>>3)&3) on stage.
template<int MODE, int NB>
__global__ __launch_bounds__(256) void gemm_k512(const short* __restrict__ W,
    const short* __restrict__ act, const float* __restrict__ bias,
    const float* __restrict__ resid, void* __restrict__ outp){
  constexpr int NSF = NB / 32;      // n-frags per wave
  const int b  = blockIdx.z;
  const int m0 = blockIdx.y * 128;
  const int n0 = blockIdx.x * NB;
  const int tid  = threadIdx.x;
  const int lane = tid & 63, w = tid >> 6;
  const int wm = w >> 1, wn = w & 1;
  const int lm = lane & 15, lb = lane >> 4;
  const int xr = (lm >> 1) & 3;     // row-swizzle term for frag reads

  __shared__ short As[2][128*32];
  __shared__ short Bs[2][NB*32];

  const short* actb = act + (size_t)b * 524288;

  auto arow = [&](int r) -> const short* {
    if constexpr (MODE == 0){
      return actb + (size_t)(m0 + r) * 512;
    } else if constexpr (MODE == 1){
      const int m = m0 + r;
      return W + (size_t)(192*(m>>6) + 128 + (m&63)) * 512;
    } else {
      return W + (size_t)(m0 + r) * 512;
    }
  };
  auto brow = [&](int r) -> const short* {
    if constexpr (MODE == 0){
      const int o = n0 + r;
      return W + (size_t)(192*((o>>6)&7) + (o&63) + ((o>=512)?64:0)) * 512;
    } else {
      return actb + (size_t)(n0 + r) * 512;
    }
  };

  // stage K-tile t into buf: async gload_lds; source chunk pre-swizzled
  auto stage = [&](int t, int buf){
    const int k0 = t * 32;
    #pragma unroll
    for (int i = 0; i < 2; ++i){
      const int c = tid + i*256;
      const int r = c >> 2, sj = (c & 3) ^ ((c >> 3) & 3);
      gload16(arow(r) + k0 + sj*8, &As[buf][(c>>2)*32 + (c&3)*8]);
    }
    #pragma unroll
    for (int i = 0; i < NB/64; ++i){
      const int c = tid + i*256;
      const int r = c >> 2, sj = (c & 3) ^ ((c >> 3) & 3);
      gload16(brow(r) + k0 + sj*8, &Bs[buf][(c>>2)*32 + (c&3)*8]);
    }
  };

  f32x4 acc[4][NSF] = {};
  stage(0, 0);

  for (int t = 0; t < 16; ++t){
    __syncthreads();                 // waits vmcnt(0) for prior stage
    if (t + 1 < 16) stage(t + 1, (t + 1) & 1);
    const int buf = t & 1;

    s16x8 af[4], bfr[NSF];
    #pragma unroll
    for (int ms = 0; ms < 4; ++ms){
      const int row = wm*64 + ms*16 + lm;
      af[ms] = *(const s16x8*)&As[buf][row*32 + ((lb ^ xr) << 3)];
    }
    #pragma unroll
    for (int ns = 0; ns < NSF; ++ns){
      const int row = wn*(NB/2) + ns*16 + lm;
      bfr[ns] = *(const s16x8*)&Bs[buf][row*32 + ((lb ^ xr) << 3)];
    }
    #pragma unroll
    for (int ns = 0; ns < NSF; ++ns)
      #pragma unroll
      for (int ms = 0; ms < 4; ++ms)
        acc[ms][ns] = mfma_bf16_16x16x32(af[ms], bfr[ns], acc[ms][ns]);
  }

  // C/D: col = lane&15, row = 4*(lane>>4) + reg   (m89)
  const int mo = m0 + wm*64, no = n0 + wn*(NB/2);
  if constexpr (MODE == 0){
    short* out = (short*)outp + (size_t)b * 1048576;
    float bn[NSF];
    #pragma unroll
    for (int ns = 0; ns < NSF; ++ns){
      const int o = no + ns*16 + lm;
      bn[ns] = QK_SCALE * bias[192*((o>>6)&7) + (o&63) + ((o>=512)?64:0)];
    }
    #pragma unroll
    for (int ms = 0; ms < 4; ++ms)
      #pragma unroll
      for (int ns = 0; ns < NSF; ++ns)
        #pragma unroll
        for (int r = 0; r < 4; ++r){
          const int m = mo + ms*16 + 4*lb + r;
          const int n = no + ns*16 + lm;
          out[(size_t)m*1024 + n] = f2bf(acc[ms][ns][r] + bn[ns]);
        }
  } else if constexpr (MODE == 1){
    short* out = (short*)outp + (size_t)b * 524288;
    float bm[16];
    #pragma unroll
    for (int ms = 0; ms < 4; ++ms)
      #pragma unroll
      for (int r = 0; r < 4; ++r){
        const int m = mo + ms*16 + 4*lb + r;
        bm[ms*4+r] = bias[192*(m>>6) + 128 + (m&63)];
      }
    #pragma unroll
    for (int ms = 0; ms < 4; ++ms)
      #pragma unroll
      for (int ns = 0; ns < NSF; ++ns)
        #pragma unroll
        for (int r = 0; r < 4; ++r){
          const int m = mo + ms*16 + 4*lb + r;
          const int n = no + ns*16 + lm;
          out[(size_t)m*1024 + n] = f2bf(acc[ms][ns][r] + bm[ms*4+r]);
        }
  } else {
    float* out = (float*)outp + (size_t)b * 524288;
    const float* xr2 = resid + (size_t)b * 524288;
    #pragma unroll
    for (int ms = 0; ms < 4; ++ms)
      #pragma unroll
      for (int ns = 0; ns < NSF; ++ns)
        #pragma unroll
        for (int r = 0; r < 4; ++r){
          const int m = mo + ms*16 + 4*lb + r;
          const int n = no + ns*16 + lm;
          out[(size_t)m*1024 + n] = acc[ms][ns][r] + bias[m] + xr2[(size_t)m*1024 + n];
        }
  }
}

// ---------------------------------------------------------------------------
// Attention v6: attn3 structure (512 blocks x 256 thr, 4 waves x 32t, KVBLK=64,
// dbuf, 35840B LDS -> 2 blk/CU) + deferred l-sum (no sum shuffles in loop) +
// max3 fmax tree + setprio. bid = bh + 64*tc (XCD locality).
__global__ __launch_bounds__(256) void attn6_kernel(const short* __restrict__ qkT,
    const short* __restrict__ vbuf, short* __restrict__ attT){
  const int bid = blockIdx.x;
  const int bh = bid & 63, tc = bid >> 6;
  const int b = bh >> 3, h = bh & 7;
  const int tid = threadIdx.x;
  const int lane = tid & 63, w = tid >> 6;
  const int lm = lane & 15, lb = lane >> 4;
  const int t0 = tc * 128;

  const short* qb = qkT + (size_t)b*1048576 + h*64;
  const short* kb = qkT + (size_t)b*1048576 + 512 + h*64;
  const short* vb = vbuf + (size_t)b*524288 + (size_t)(h*64)*1024;

  __shared__ short Ks[2][64*72];    // [s][c] pad 72
  __shared__ short Vs[2][64*68];    // [c][s] pad 68

  // Q frags straight from global (read-once), contiguous k-map
  s16x8 qf[2][2];
  #pragma unroll
  for (int tb = 0; tb < 2; ++tb)
    #pragma unroll
    for (int ks = 0; ks < 2; ++ks)
      qf[tb][ks] = *(const s16x8*)(qb + (size_t)(t0 + w*32 + tb*16 + lm)*1024
                                      + ks*32 + 8*lb);

  uint4 kreg[2], vreg[2];
  auto load_kv = [&](int it){
    const int s0 = it * 64;
    #pragma unroll
    for (int i = 0; i < 2; ++i){
      const int g = tid + i*256, r = g >> 3, c8 = g & 7;
      kreg[i] = *(const uint4*)(kb + (size_t)(s0 + r)*1024 + c8*8);
      vreg[i] = *(const uint4*)(vb + (size_t)r*1024 + s0 + c8*8);
    }
  };
  auto write_kv = [&](int buf){
    #pragma unroll
    for (int i = 0; i < 2; ++i){
      const int g = tid + i*256, r = g >> 3, c8 = g & 7;
      *(uint4*)&Ks[buf][r*72 + c8*8] = kreg[i];
      *(uint2*)&Vs[buf][r*68 + c8*8]     = make_uint2(vreg[i].x, vreg[i].y);
      *(uint2*)&Vs[buf][r*68 + c8*8 + 4] = make_uint2(vreg[i].z, vreg[i].w);
    }
  };

  f32x4 of[2][4] = {};
  float mrun[2] = {-1e30f, -1e30f}, lrun[2] = {0.f, 0.f};  // lrun: per-lane partial
  s16x8 pbf[2][2];

  load_kv(0);
  write_kv(0);

  for (int it = 0; it < 16; ++it){
    if (it + 1 < 16) load_kv(it + 1);
    __syncthreads();
    const int buf = it & 1;

    // QK^T: S'[s][t], contiguous k-map, single b128 K-frags
    f32x4 sf[2][4];
    #pragma unroll
    for (int tb = 0; tb < 2; ++tb)
      #pragma unroll
      for (int ms = 0; ms < 4; ++ms) sf[tb][ms] = 0.f;
    __builtin_amdgcn_s_setprio(1);
    #pragma unroll
    for (int ks = 0; ks < 2; ++ks){
      s16x8 kf[4];
      #pragma unroll
      for (int ms = 0; ms < 4; ++ms)
        kf[ms] = *(const s16x8*)&Ks[buf][(ms*16 + lm)*72 + ks*32 + 8*lb];
      #pragma unroll
      for (int ms = 0; ms < 4; ++ms){
        sf[0][ms] = mfma_bf16_16x16x32(kf[ms], qf[0][ks], sf[0][ms]);
        sf[1][ms] = mfma_bf16_16x16x32(kf[ms], qf[1][ks], sf[1][ms]);
      }
    }
    __builtin_amdgcn_s_setprio(0);

    // online softmax (log2 domain), defer-max THR=8, deferred l-sum
    #pragma unroll
    for (int tb = 0; tb < 2; ++tb){
      const float a0 = FMAX3(sf[tb][0][0], sf[tb][0][1], sf[tb][0][2]);
      const float a1 = FMAX3(sf[tb][0][3], sf[tb][1][0], sf[tb][1][1]);
      const float a2 = FMAX3(sf[tb][1][2], sf[tb][1][3], sf[tb][2][0]);
      const float a3 = FMAX3(sf[tb][2][1], sf[tb][2][2], sf[tb][2][3]);
      const float a4 = FMAX3(sf[tb][3][0], sf[tb][3][1], sf[tb][3][2]);
      float mt = fmaxf(FMAX3(a0, a1, a2), FMAX3(a3, a4, sf[tb][3][3]));
      mt = fmaxf(mt, __shfl_xor(mt, 16, 64));
      mt = fmaxf(mt, __shfl_xor(mt, 32, 64));
      const bool allskip = __all(mt <= mrun[tb] + 8.f);
      const float mnew = allskip ? mrun[tb] : fmaxf(mrun[tb], mt);
      float ps = 0.f;
      #pragma unroll
      for (int ms = 0; ms < 4; ++ms)
        #pragma unroll
        for (int r = 0; r < 4; ++r){
          const float e = exp2f(sf[tb][ms][r] - mnew);
          ps += e;
          pbf[tb][ms >> 1][(ms & 1)*4 + r] = f2bf(e);
        }
      if (allskip){
        lrun[tb] += ps;            // per-lane partial; cross-lane sum deferred
      } else {
        const float alpha = exp2f(mrun[tb] - mnew);
        lrun[tb] = lrun[tb]*alpha + ps;
        mrun[tb] = mnew;
        #pragma unroll
        for (int cs = 0; cs < 4; ++cs) of[tb][cs] *= alpha;
      }
    }

    // PV: D[c][t] = mfma(A=V rows, B=P'); k-map (j>>2)*16+4lb+(j&3), b64 pairs
    __builtin_amdgcn_s_setprio(1);
    #pragma unroll
    for (int ks2 = 0; ks2 < 2; ++ks2)
      #pragma unroll
      for (int cs = 0; cs < 4; ++cs){
        const short* pV = &Vs[buf][(cs*16 + lm)*68 + ks2*32 + 4*lb];
        s16x8 vf = cat8(*(const s16x4*)pV, *(const s16x4*)(pV + 16));
        of[0][cs] = mfma_bf16_16x16x32(vf, pbf[0][ks2], of[0][cs]);
        of[1][cs] = mfma_bf16_16x16x32(vf, pbf[1][ks2], of[1][cs]);
      }
    __builtin_amdgcn_s_setprio(0);

    if (it + 1 < 16) write_kv((it + 1) & 1);
  }

  // epilogue: reduce deferred l partials (once), then transpose via LDS.
  #pragma unroll
  for (int tb = 0; tb < 2; ++tb){
    lrun[tb] += __shfl_xor(lrun[tb], 16, 64);
    lrun[tb] += __shfl_xor(lrun[tb], 32, 64);
  }
  __syncthreads();
  short* Tl = &Ks[0][0];                       // 128 x 72 shorts
  const float inv0 = 1.f / lrun[0], inv1 = 1.f / lrun[1];
  #pragma unroll
  for (int tb = 0; tb < 2; ++tb)
    #pragma unroll
    for (int cs = 0; cs < 4; ++cs){
      s16x4 o;
      #pragma unroll
      for (int r = 0; r < 4; ++r)
        o[r] = f2bf(of[tb][cs][r] * (tb ? inv1 : inv0));
      *(s16x4*)&Tl[(w*32 + tb*16 + lm)*72 + cs*16 + 4*lb] = o;
    }
  __syncthreads();
  short* outb = attT + (size_t)b*524288 + (size_t)t0*512 + h*64;
  #pragma unroll
  for (int i = 0; i < 4; ++i){
    const int g = tid + i*256, r = g >> 3, c8 = g & 7;
    *(uint4*)(outb + (size_t)r*512 + c8*8) = *(const uint4*)&Tl[r*72 + c8*8];
  }
}

// ---------------------------------------------------------------------------
extern "C" void kernel_launch(void* const* d_in, const int* in_sizes, int n_in,
                              void* d_out, int out_size, void* d_ws, size_t ws_size,
                              hipStream_t stream){
  const float* x      = (const float*)d_in[0];
  const float* norm_w = (const float*)d_in[1];
  const float* norm_b = (const float*)d_in[2];
  const float* qkv_w  = (const float*)d_in[3];
  const float* qkv_b  = (const float*)d_in[4];
  const float* proj_w = (const float*)d_in[5];
  const float* proj_b = (const float*)d_in[6];

  char* ws = (char*)d_ws;
  float2* stats = (float2*)(ws);                                   //   4 KB
  short*  xnT   = (short*)(ws + 4096);                             //   8 MiB
  short*  qwb   = (short*)(ws + 4096 + 8388608);                   // 1.5 MiB
  short*  pwb   = (short*)(ws + 4096 + 8388608 + 1572864);         // 0.5 MiB
  short*  qkT   = (short*)(ws + 4096 + 8388608 + 1572864 + 524288);            // 16 MiB
  short*  vbuf  = (short*)(ws + 4096 + 8388608 + 1572864 + 524288 + 16777216); //  8 MiB
  short*  attT  = (short*)(ws + 4096 + 8388608 + 1572864 + 524288 + 16777216 + 8388608); // 8 MiB

  gn_stats_kernel<<<dim3(256), dim3(256), 0, stream>>>(x, stats);
  gn_norm_t_kernel<<<dim3(16, 8), dim3(256), 0, stream>>>(x, norm_w, norm_b, stats, xnT);
  cvt_w_kernel<<<dim3(512), dim3(256), 0, stream>>>(qkv_w, proj_w, qwb, pwb);
  gemm_k512<0,128><<<dim3(8, 8, 8), dim3(256), 0, stream>>>(qwb, xnT, qkv_b, nullptr, (void*)qkT);
  gemm_k512<1,64><<<dim3(16, 4, 8), dim3(256), 0, stream>>>(qwb, xnT, qkv_b, nullptr, (void*)vbuf);
  attn6_kernel<<<dim3(512), dim3(256), 0, stream>>>(qkT, vbuf, attT);
  gemm_k512<2,64><<<dim3(16, 4, 8), dim3(256), 0, stream>>>(pwb, attT, proj_b, x, d_out);
}